// Round 7
// baseline (174.026 us; speedup 1.0000x reference)
//
#include <hip/hip_runtime.h>
#include <hip/hip_bf16.h>

// DotProductAttention (Swin windowed, masked softmax).
// Inputs FP32. n=1024, Q=K=256, d=32, num_windows=64, NUM_HEADS=8.
// R10: PV without LDS bounces. R6 left a block tail of LDS round-trips:
//  P-bounce (write+fence+read x2), O-bounce (fence+write+fence+read), and
//  barrier C coupling all waves. Register file (acc 64 AGPR + ~50 arch)
//  caps occupancy at 4 waves/SIMD regardless of LDS -> the lever is the
//  per-block serial chain, not blocks/CU.
//  History: R0 127 | R1 144 | R2 215 | R3 155 | R4 72 | R6 68.5 (us/dispatch).
//  - P redistribution C-layout -> B-frag done IN REGISTERS: lane (c,q) needs
//    P[c][32kt+8q+j'] = tile 2kt+(q>=2), src lane c+32(q&1) (dw0,1) and
//    c+16+32(q&1) (dw2,3) -> 8 __shfl + 4 cndmask per kt (verified
//    element-wise vs the working bounce semantics). No P LDS, no fences,
//    NO barrier C: waves decouple after staging.
//  - direct O^T store: lane (c,q) holds O[qbase+c][4q+j] (o0) / +16 (o1);
//    two float4 stores/lane = 16 full 64B sectors per instruction -> same
//    coalescing as the old bounce, zero LDS.
//  - pk[16] (32 regs) persistent through PV; mraw gone since R6 -> fits.
//  - everything else R6-proven: 4096 blocks (one (b,qt) each), K row-major
//    bf16 LDS + mask-as-C_in S-MFMA, scale folded into Q pack, no-max exp
//    (bounds-safe), V^T bf16 LDS, XCD window pinning, launch_bounds(256,4).

typedef __attribute__((ext_vector_type(8))) short short8;   // 8 bf16 = 4 VGPR
typedef __attribute__((ext_vector_type(4))) float floatx4;  // MFMA C/D

#define KSTRIDE 40    // ushorts per K row (32 + 8 pad; 80 B, mult of 16)
#define VSTRIDE 264   // ushorts per Vt row (256 + 8 pad; 528 B, mult of 16)
#define NEGV -1000000.0f

static __device__ __forceinline__ unsigned packbf2(float a, float b) {
    union { __hip_bfloat162 h2; unsigned u; } x;
    x.h2 = __float22bfloat162_rn(make_float2(a, b));   // hw v_cvt_pk_bf16_f32
    return x.u;
}

union S8U { short8 s8; unsigned u[4]; };

__global__ __launch_bounds__(256, 4)
void attn_swin_kernel(const float* __restrict__ Qg,
                      const float* __restrict__ Kg,
                      const float* __restrict__ Vg,
                      const int* __restrict__ VLg,
                      const float* __restrict__ Wg,
                      float* __restrict__ Og)
{
    __shared__ __align__(16) unsigned short Ksh[256 * KSTRIDE]; // 20.0 KB
    __shared__ __align__(16) unsigned short Vt[32 * VSTRIDE];   // 16.5 KB  V^T: Vt[d][k]

    const int tid  = threadIdx.x;
    const int lane = tid & 63;
    const int c    = lane & 15;   // MFMA column (= q within wave's 16 rows)
    const int quad = lane >> 4;   // 0..3

    // blk -> (xcd, qt, bat, wl): 4096 blocks, window pinned to one XCD
    const int blk = blockIdx.x;
    const int xcd = blk & 7;
    const int j   = blk >> 3;          // 0..511
    const int qt  = j & 3;
    const int bat = (j >> 2) & 15;     // 0..15 batch-in-window
    const int wl  = j >> 6;            // 0..7
    const int w   = xcd + 8 * wl;      // 0..63
    const int b   = (bat >> 3) * 512 + w * 8 + (bat & 7);
    const int qbase = qt * 64 + (tid >> 6) * 16;
    const size_t bb = (size_t)b * 8192;

    // valid_lens dtype probe (values in [1,256]): int64 layout => word 1 == 0
    const bool vl64 = (VLg[1] == 0);
    int vl = vl64 ? (int)(((const long long*)VLg)[b]) : VLg[b];
    vl = min(max(vl, 0), 256);

    const int r0 = tid >> 3;          // staging: row within 32-row chunk
    const int d0 = (tid & 7) * 4;     // staging: first of 4 d's

    // ---- stage K as bf16 row-major (8 coalesced float4, fully unrolled) ----
    {
        const float* kp = Kg + bb + tid * 4;
        float4 k0 = *(const float4*)(kp);
        float4 k1 = *(const float4*)(kp + 1024);
        float4 k2 = *(const float4*)(kp + 2048);
        float4 k3 = *(const float4*)(kp + 3072);
        float4 k4 = *(const float4*)(kp + 4096);
        float4 k5 = *(const float4*)(kp + 5120);
        float4 k6 = *(const float4*)(kp + 6144);
        float4 k7 = *(const float4*)(kp + 7168);
        #pragma unroll
        for (int ch = 0; ch < 8; ++ch) {
            float4 kv = (ch == 0) ? k0 : (ch == 1) ? k1 : (ch == 2) ? k2 :
                        (ch == 3) ? k3 : (ch == 4) ? k4 : (ch == 5) ? k5 :
                        (ch == 6) ? k6 : k7;
            uint2 kk;
            kk.x = packbf2(kv.x, kv.y);
            kk.y = packbf2(kv.z, kv.w);
            *(uint2*)&Ksh[(ch * 32 + r0) * KSTRIDE + d0] = kk;   // ds_write_b64
        }
    }

    // ---- stage V as bf16 transposed ----
    {
        const float* vp = Vg + bb + tid * 4;
        float4 v0 = *(const float4*)(vp);
        float4 v1 = *(const float4*)(vp + 1024);
        float4 v2 = *(const float4*)(vp + 2048);
        float4 v3 = *(const float4*)(vp + 3072);
        float4 v4 = *(const float4*)(vp + 4096);
        float4 v5 = *(const float4*)(vp + 5120);
        float4 v6 = *(const float4*)(vp + 6144);
        float4 v7 = *(const float4*)(vp + 7168);
        #pragma unroll
        for (int ch = 0; ch < 8; ++ch) {
            float4 vv = (ch == 0) ? v0 : (ch == 1) ? v1 : (ch == 2) ? v2 :
                        (ch == 3) ? v3 : (ch == 4) ? v4 : (ch == 5) ? v5 :
                        (ch == 6) ? v6 : v7;
            const int row = ch * 32 + r0;
            unsigned p0 = packbf2(vv.x, vv.y);
            unsigned p1 = packbf2(vv.z, vv.w);
            Vt[(d0 + 0) * VSTRIDE + row] = (unsigned short)(p0 & 0xffffu);
            Vt[(d0 + 1) * VSTRIDE + row] = (unsigned short)(p0 >> 16);
            Vt[(d0 + 2) * VSTRIDE + row] = (unsigned short)(p1 & 0xffffu);
            Vt[(d0 + 3) * VSTRIDE + row] = (unsigned short)(p1 >> 16);
        }
    }

    // ---- Q B-frag with scale FOLDED IN (S = K·(Q*s)^T = s·K·Q^T) ----
    const float scale = 0.17677669529663687f;  // 1/sqrt(32)
    short8 qb;
    {
        const float* qp = Qg + bb + (size_t)(qbase + c) * 32 + quad * 8;
        float4 q0 = *(const float4*)qp;
        float4 q1 = *(const float4*)(qp + 4);
        S8U t2;
        t2.u[0] = packbf2(q0.x * scale, q0.y * scale);
        t2.u[1] = packbf2(q0.z * scale, q0.w * scale);
        t2.u[2] = packbf2(q1.x * scale, q1.y * scale);
        t2.u[3] = packbf2(q1.z * scale, q1.w * scale);
        qb = t2.s8;
    }

    // ---- mask group 1 (8 float4, 32 regs): issued before the barrier ----
    const float* wp = Wg + (size_t)w * 65536 + (size_t)(qbase + c) * 256 + quad * 4;
    float4 ma[8];
    #pragma unroll
    for (int t = 0; t < 8; ++t) ma[t] = *(const float4*)(wp + t * 16);

    __syncthreads();   // B: Ksh/Vt visible (the ONLY barrier)

    // ---- S^T = K*(Q·s)^T + M^T  (mask rides in as MFMA C_in) ----
    floatx4 acc[16];
    #pragma unroll
    for (int t = 0; t < 8; ++t) {
        short8 ka = *(const short8*)&Ksh[(t * 16 + c) * KSTRIDE + quad * 8];
        floatx4 cin = {ma[t].x, ma[t].y, ma[t].z, ma[t].w};
        acc[t] = __builtin_amdgcn_mfma_f32_16x16x32_bf16(ka, qb, cin, 0, 0, 0);
    }
    #pragma unroll
    for (int t = 0; t < 8; ++t) ma[t] = *(const float4*)(wp + (t + 8) * 16);   // group 2
    #pragma unroll
    for (int t = 8; t < 16; ++t) {
        short8 ka = *(const short8*)&Ksh[(t * 16 + c) * KSTRIDE + quad * 8];
        floatx4 cin = {ma[t - 8].x, ma[t - 8].y, ma[t - 8].z, ma[t - 8].w};
        acc[t] = __builtin_amdgcn_mfma_f32_16x16x32_bf16(ka, qb, cin, 0, 0, 0);
    }

    // ---- valid-len mask + plain exp (no max pass; bounds-safe) + sum;
    //      pack P to bf16 pairs in registers (pk feeds the shuffle-PV) ----
    float l0 = 0.f, l1 = 0.f;
    uint2 pk[16];
    #pragma unroll
    for (int t = 0; t < 16; ++t) {
        float s0 = acc[t][0], s1 = acc[t][1], s2 = acc[t][2], s3 = acc[t][3];
        if ((t + 1) * 16 > vl) {             // uniform branch (vl block-uniform)
            const int k0i = t * 16 + quad * 4;
            s0 = (k0i + 0 < vl) ? s0 : NEGV;
            s1 = (k0i + 1 < vl) ? s1 : NEGV;
            s2 = (k0i + 2 < vl) ? s2 : NEGV;
            s3 = (k0i + 3 < vl) ? s3 : NEGV;
        }
        float p0 = __expf(s0);
        float p1 = __expf(s1);
        float p2 = __expf(s2);
        float p3 = __expf(s3);
        l0 += p0 + p1;
        l1 += p2 + p3;
        pk[t].x = packbf2(p0, p1);
        pk[t].y = packbf2(p2, p3);
    }
    float l = l0 + l1;
    l += __shfl_xor(l, 16);
    l += __shfl_xor(l, 32);
    const float rl = (l > 0.f) ? (1.0f / l) : 0.f;

    // ---- PV: P B-frags assembled by cross-lane shuffle (no LDS, no fence) ----
    // lane (c,q), tile kt needs P[c][32kt+8q+j'], j'=0..7:
    //   dw0,dw1 (j'=0..3) from lane c+32(q&1); dw2,dw3 (j'=4..7) from +16;
    //   source tile = 2kt (q<2) or 2kt+1 (q>=2).
    const int srcA = c + 32 * (quad & 1);
    const int srcB = srcA + 16;
    const bool hi  = quad >= 2;

    floatx4 o0 = {0.f, 0.f, 0.f, 0.f}, o1 = {0.f, 0.f, 0.f, 0.f};
    #pragma unroll
    for (int kt = 0; kt < 8; ++kt) {
        unsigned a0x = __shfl(pk[2 * kt].x,     srcA);
        unsigned a1x = __shfl(pk[2 * kt + 1].x, srcA);
        unsigned a0y = __shfl(pk[2 * kt].y,     srcA);
        unsigned a1y = __shfl(pk[2 * kt + 1].y, srcA);
        unsigned b0x = __shfl(pk[2 * kt].x,     srcB);
        unsigned b1x = __shfl(pk[2 * kt + 1].x, srcB);
        unsigned b0y = __shfl(pk[2 * kt].y,     srcB);
        unsigned b1y = __shfl(pk[2 * kt + 1].y, srcB);
        S8U pb;
        pb.u[0] = hi ? a1x : a0x;
        pb.u[1] = hi ? a1y : a0y;
        pb.u[2] = hi ? b1x : b0x;
        pb.u[3] = hi ? b1y : b0y;
        short8 va0 = *(const short8*)&Vt[c * VSTRIDE + kt * 32 + quad * 8];
        short8 va1 = *(const short8*)&Vt[(16 + c) * VSTRIDE + kt * 32 + quad * 8];
        o0 = __builtin_amdgcn_mfma_f32_16x16x32_bf16(va0, pb.s8, o0, 0, 0, 0);
        o1 = __builtin_amdgcn_mfma_f32_16x16x32_bf16(va1, pb.s8, o1, 0, 0, 0);
    }

    // ---- normalize + DIRECT O^T store (lane (c,q): O[qbase+c][4q+j], +16) ----
    {
        float4 w0, w1;
        w0.x = o0[0] * rl; w0.y = o0[1] * rl; w0.z = o0[2] * rl; w0.w = o0[3] * rl;
        w1.x = o1[0] * rl; w1.y = o1[1] * rl; w1.z = o1[2] * rl; w1.w = o1[3] * rl;
        float* op = Og + bb + (size_t)(qbase + c) * 32 + quad * 4;
        *(float4*)op        = w0;   // d = quad*4..+3
        *(float4*)(op + 16) = w1;   // d = 16+quad*4..+3
    }
}

extern "C" void kernel_launch(void* const* d_in, const int* in_sizes, int n_in,
                              void* d_out, int out_size, void* d_ws, size_t ws_size,
                              hipStream_t stream) {
    (void)in_sizes; (void)n_in; (void)out_size; (void)d_ws; (void)ws_size;
    const float* Qg  = (const float*)d_in[0];
    const float* Kg  = (const float*)d_in[1];
    const float* Vg  = (const float*)d_in[2];
    const int*   VLg = (const int*)d_in[3];
    const float* Wg  = (const float*)d_in[4];
    float*       Og  = (float*)d_out;

    attn_swin_kernel<<<dim3(4096), dim3(256), 0, stream>>>(Qg, Kg, Vg, VLg, Wg, Og);
}

// Round 8
// 166.492 us; speedup vs baseline: 1.0453x; 1.0453x over previous
//
#include <hip/hip_runtime.h>
#include <hip/hip_bf16.h>

// DotProductAttention (Swin windowed, masked softmax).
// Inputs FP32. n=1024, Q=K=256, d=32, num_windows=64, NUM_HEADS=8.
// R11: work proportional to valid_len. R7 post-mortem: removing the P/O LDS
//  bounces was NEUTRAL (69 vs 68.5us) -> tail wasn't critical; __shfl is
//  ds_bpermute (same LDS pipe). VALUBusy 26% = ~1200 VALU inst/lane = hard
//  ~17us floor at 4 waves/SIMD (reg-capped). The lever is REMOVING work:
//  vl is block-uniform, mean ~128.5/256, and everything past vl is exactly
//  zero after masking. Skip it at uniform-branch granularity:
//   - S MFMA groups of 4 guarded by vl>64g (keeps ds_reads batched; partial
//     groups compute <=3 dead MFMAs into unread acc - harmless)
//   - exp per-tile t<used16, else pk[t]=0 (shuffle sources defined)
//   - PV per-kt kt<used32 (guard exactly matches staged V chunks -> no
//     stale/uninitialized LDS ever read)
//   - K/V staging chunk-groups guarded by vl>128 (halves the conflicted
//     u16 scatter + loads on average)
//  History: R0 127 | R1 144 | R2 215 | R3 155 | R4 72 | R6 68.5 | R7 69.2.
//  Carried: 4096 blocks (one (b,qt) each), XCD window pinning, K row-major
//  bf16 LDS, mask-as-C_in S-MFMA, scale folded into Q pack, no-max exp
//  (bounds-safe: |S|<=~12), V^T bf16 LDS, shuffle-PV (no P LDS), direct O^T
//  stores, launch_bounds(256,4), no spill (WRITE_SIZE==32MB checks it).

typedef __attribute__((ext_vector_type(8))) short short8;   // 8 bf16 = 4 VGPR
typedef __attribute__((ext_vector_type(4))) float floatx4;  // MFMA C/D

#define KSTRIDE 40    // ushorts per K row (32 + 8 pad; 80 B, mult of 16)
#define VSTRIDE 264   // ushorts per Vt row (256 + 8 pad; 528 B, mult of 16)
#define NEGV -1000000.0f

static __device__ __forceinline__ unsigned packbf2(float a, float b) {
    union { __hip_bfloat162 h2; unsigned u; } x;
    x.h2 = __float22bfloat162_rn(make_float2(a, b));   // hw v_cvt_pk_bf16_f32
    return x.u;
}

union S8U { short8 s8; unsigned u[4]; };

__global__ __launch_bounds__(256, 4)
void attn_swin_kernel(const float* __restrict__ Qg,
                      const float* __restrict__ Kg,
                      const float* __restrict__ Vg,
                      const int* __restrict__ VLg,
                      const float* __restrict__ Wg,
                      float* __restrict__ Og)
{
    __shared__ __align__(16) unsigned short Ksh[256 * KSTRIDE]; // 20.0 KB
    __shared__ __align__(16) unsigned short Vt[32 * VSTRIDE];   // 16.5 KB  V^T: Vt[d][k]

    const int tid  = threadIdx.x;
    const int lane = tid & 63;
    const int c    = lane & 15;   // MFMA column (= q within wave's 16 rows)
    const int quad = lane >> 4;   // 0..3

    // blk -> (xcd, qt, bat, wl): 4096 blocks, window pinned to one XCD
    const int blk = blockIdx.x;
    const int xcd = blk & 7;
    const int j   = blk >> 3;          // 0..511
    const int qt  = j & 3;
    const int bat = (j >> 2) & 15;     // 0..15 batch-in-window
    const int wl  = j >> 6;            // 0..7
    const int w   = xcd + 8 * wl;      // 0..63
    const int b   = (bat >> 3) * 512 + w * 8 + (bat & 7);
    const int qbase = qt * 64 + (tid >> 6) * 16;
    const size_t bb = (size_t)b * 8192;

    // valid_lens dtype probe (values in [1,256]): int64 layout => word 1 == 0
    const bool vl64 = (VLg[1] == 0);
    int vl = vl64 ? (int)(((const long long*)VLg)[b]) : VLg[b];
    vl = min(max(vl, 0), 256);
    const int used16 = (vl + 15) >> 4;   // S tiles needed
    const int used32 = (vl + 31) >> 5;   // PV kt / staging chunks needed

    const int r0 = tid >> 3;          // staging: row within 32-row chunk
    const int d0 = (tid & 7) * 4;     // staging: first of 4 d's

    // ---- stage K as bf16 row-major (chunk groups guarded by vl) ----
    const float* kp = Kg + bb + tid * 4;
    {
        float4 k0 = *(const float4*)(kp);
        float4 k1 = *(const float4*)(kp + 1024);
        float4 k2 = *(const float4*)(kp + 2048);
        float4 k3 = *(const float4*)(kp + 3072);
        #pragma unroll
        for (int ch = 0; ch < 4; ++ch) {
            float4 kv = (ch == 0) ? k0 : (ch == 1) ? k1 : (ch == 2) ? k2 : k3;
            uint2 kk;
            kk.x = packbf2(kv.x, kv.y);
            kk.y = packbf2(kv.z, kv.w);
            *(uint2*)&Ksh[(ch * 32 + r0) * KSTRIDE + d0] = kk;   // ds_write_b64
        }
    }
    if (vl > 128) {
        float4 k4 = *(const float4*)(kp + 4096);
        float4 k5 = *(const float4*)(kp + 5120);
        float4 k6 = *(const float4*)(kp + 6144);
        float4 k7 = *(const float4*)(kp + 7168);
        #pragma unroll
        for (int ch = 4; ch < 8; ++ch) {
            float4 kv = (ch == 4) ? k4 : (ch == 5) ? k5 : (ch == 6) ? k6 : k7;
            uint2 kk;
            kk.x = packbf2(kv.x, kv.y);
            kk.y = packbf2(kv.z, kv.w);
            *(uint2*)&Ksh[(ch * 32 + r0) * KSTRIDE + d0] = kk;
        }
    }

    // ---- stage V as bf16 transposed (chunk groups guarded by vl) ----
    const float* vp = Vg + bb + tid * 4;
    {
        float4 v0 = *(const float4*)(vp);
        float4 v1 = *(const float4*)(vp + 1024);
        float4 v2 = *(const float4*)(vp + 2048);
        float4 v3 = *(const float4*)(vp + 3072);
        #pragma unroll
        for (int ch = 0; ch < 4; ++ch) {
            float4 vv = (ch == 0) ? v0 : (ch == 1) ? v1 : (ch == 2) ? v2 : v3;
            const int row = ch * 32 + r0;
            unsigned p0 = packbf2(vv.x, vv.y);
            unsigned p1 = packbf2(vv.z, vv.w);
            Vt[(d0 + 0) * VSTRIDE + row] = (unsigned short)(p0 & 0xffffu);
            Vt[(d0 + 1) * VSTRIDE + row] = (unsigned short)(p0 >> 16);
            Vt[(d0 + 2) * VSTRIDE + row] = (unsigned short)(p1 & 0xffffu);
            Vt[(d0 + 3) * VSTRIDE + row] = (unsigned short)(p1 >> 16);
        }
    }
    if (vl > 128) {
        float4 v4 = *(const float4*)(vp + 4096);
        float4 v5 = *(const float4*)(vp + 5120);
        float4 v6 = *(const float4*)(vp + 6144);
        float4 v7 = *(const float4*)(vp + 7168);
        #pragma unroll
        for (int ch = 4; ch < 8; ++ch) {
            float4 vv = (ch == 4) ? v4 : (ch == 5) ? v5 : (ch == 6) ? v6 : v7;
            const int row = ch * 32 + r0;
            unsigned p0 = packbf2(vv.x, vv.y);
            unsigned p1 = packbf2(vv.z, vv.w);
            Vt[(d0 + 0) * VSTRIDE + row] = (unsigned short)(p0 & 0xffffu);
            Vt[(d0 + 1) * VSTRIDE + row] = (unsigned short)(p0 >> 16);
            Vt[(d0 + 2) * VSTRIDE + row] = (unsigned short)(p1 & 0xffffu);
            Vt[(d0 + 3) * VSTRIDE + row] = (unsigned short)(p1 >> 16);
        }
    }

    // ---- Q B-frag with scale FOLDED IN (S = K·(Q*s)^T = s·K·Q^T) ----
    const float scale = 0.17677669529663687f;  // 1/sqrt(32)
    short8 qb;
    {
        const float* qp = Qg + bb + (size_t)(qbase + c) * 32 + quad * 8;
        float4 q0 = *(const float4*)qp;
        float4 q1 = *(const float4*)(qp + 4);
        S8U t2;
        t2.u[0] = packbf2(q0.x * scale, q0.y * scale);
        t2.u[1] = packbf2(q0.z * scale, q0.w * scale);
        t2.u[2] = packbf2(q1.x * scale, q1.y * scale);
        t2.u[3] = packbf2(q1.z * scale, q1.w * scale);
        qb = t2.s8;
    }

    // ---- mask batch 1 (tiles 0-7; 32 regs): issued before the barrier ----
    const float* wp = Wg + (size_t)w * 65536 + (size_t)(qbase + c) * 256 + quad * 4;
    float4 ma[8];
    #pragma unroll
    for (int t = 0; t < 8; ++t) ma[t] = *(const float4*)(wp + t * 16);

    __syncthreads();   // B: Ksh/Vt visible (the ONLY barrier)

    // ---- S^T = K*(Q·s)^T + M^T, mask as C_in; groups of 4, vl-guarded ----
    floatx4 acc[16];
    #pragma unroll
    for (int t = 0; t < 4; ++t) {               // g0: always (vl >= 1)
        short8 ka = *(const short8*)&Ksh[(t * 16 + c) * KSTRIDE + quad * 8];
        floatx4 cin = {ma[t].x, ma[t].y, ma[t].z, ma[t].w};
        acc[t] = __builtin_amdgcn_mfma_f32_16x16x32_bf16(ka, qb, cin, 0, 0, 0);
    }
    if (vl > 64) {
        #pragma unroll
        for (int t = 4; t < 8; ++t) {           // g1
            short8 ka = *(const short8*)&Ksh[(t * 16 + c) * KSTRIDE + quad * 8];
            floatx4 cin = {ma[t].x, ma[t].y, ma[t].z, ma[t].w};
            acc[t] = __builtin_amdgcn_mfma_f32_16x16x32_bf16(ka, qb, cin, 0, 0, 0);
        }
    }
    if (vl > 128) {
        #pragma unroll
        for (int t = 0; t < 8; ++t) ma[t] = *(const float4*)(wp + (t + 8) * 16);  // batch 2
        #pragma unroll
        for (int t = 8; t < 12; ++t) {          // g2
            short8 ka = *(const short8*)&Ksh[(t * 16 + c) * KSTRIDE + quad * 8];
            floatx4 cin = {ma[t - 8].x, ma[t - 8].y, ma[t - 8].z, ma[t - 8].w};
            acc[t] = __builtin_amdgcn_mfma_f32_16x16x32_bf16(ka, qb, cin, 0, 0, 0);
        }
        if (vl > 192) {
            #pragma unroll
            for (int t = 12; t < 16; ++t) {     // g3
                short8 ka = *(const short8*)&Ksh[(t * 16 + c) * KSTRIDE + quad * 8];
                floatx4 cin = {ma[t - 8].x, ma[t - 8].y, ma[t - 8].z, ma[t - 8].w};
                acc[t] = __builtin_amdgcn_mfma_f32_16x16x32_bf16(ka, qb, cin, 0, 0, 0);
            }
        }
    }

    // ---- valid-len mask + plain exp (no max pass; bounds-safe) + sum;
    //      pack P to bf16; invalid tiles -> pk=0 (shuffle sources defined) ----
    float l0 = 0.f, l1 = 0.f;
    uint2 pk[16];
    #pragma unroll
    for (int t = 0; t < 16; ++t) {
        if (t < used16) {                        // uniform (vl block-uniform)
            float s0 = acc[t][0], s1 = acc[t][1], s2 = acc[t][2], s3 = acc[t][3];
            if ((t + 1) * 16 > vl) {             // boundary tile only
                const int k0i = t * 16 + quad * 4;
                s0 = (k0i + 0 < vl) ? s0 : NEGV;
                s1 = (k0i + 1 < vl) ? s1 : NEGV;
                s2 = (k0i + 2 < vl) ? s2 : NEGV;
                s3 = (k0i + 3 < vl) ? s3 : NEGV;
            }
            float p0 = __expf(s0);
            float p1 = __expf(s1);
            float p2 = __expf(s2);
            float p3 = __expf(s3);
            l0 += p0 + p1;
            l1 += p2 + p3;
            pk[t].x = packbf2(p0, p1);
            pk[t].y = packbf2(p2, p3);
        } else {
            pk[t].x = 0u;
            pk[t].y = 0u;
        }
    }
    float l = l0 + l1;
    l += __shfl_xor(l, 16);
    l += __shfl_xor(l, 32);
    const float rl = (l > 0.f) ? (1.0f / l) : 0.f;

    // ---- PV: P B-frags by cross-lane shuffle; per-kt vl guard ----
    // lane (c,q), tile kt needs P[c][32kt+8q+j'], j'=0..7:
    //   dw0,dw1 (j'=0..3) from lane c+32(q&1); dw2,dw3 (j'=4..7) from +16;
    //   source tile = 2kt (q<2) or 2kt+1 (q>=2).
    const int srcA = c + 32 * (quad & 1);
    const int srcB = srcA + 16;
    const bool hi  = quad >= 2;

    floatx4 o0 = {0.f, 0.f, 0.f, 0.f}, o1 = {0.f, 0.f, 0.f, 0.f};
    #pragma unroll
    for (int kt = 0; kt < 8; ++kt) {
        if (kt < used32) {                       // uniform; matches staged chunks
            unsigned a0x = __shfl(pk[2 * kt].x,     srcA);
            unsigned a1x = __shfl(pk[2 * kt + 1].x, srcA);
            unsigned a0y = __shfl(pk[2 * kt].y,     srcA);
            unsigned a1y = __shfl(pk[2 * kt + 1].y, srcA);
            unsigned b0x = __shfl(pk[2 * kt].x,     srcB);
            unsigned b1x = __shfl(pk[2 * kt + 1].x, srcB);
            unsigned b0y = __shfl(pk[2 * kt].y,     srcB);
            unsigned b1y = __shfl(pk[2 * kt + 1].y, srcB);
            S8U pb;
            pb.u[0] = hi ? a1x : a0x;
            pb.u[1] = hi ? a1y : a0y;
            pb.u[2] = hi ? b1x : b0x;
            pb.u[3] = hi ? b1y : b0y;
            short8 va0 = *(const short8*)&Vt[c * VSTRIDE + kt * 32 + quad * 8];
            short8 va1 = *(const short8*)&Vt[(16 + c) * VSTRIDE + kt * 32 + quad * 8];
            o0 = __builtin_amdgcn_mfma_f32_16x16x32_bf16(va0, pb.s8, o0, 0, 0, 0);
            o1 = __builtin_amdgcn_mfma_f32_16x16x32_bf16(va1, pb.s8, o1, 0, 0, 0);
        }
    }

    // ---- normalize + DIRECT O^T store (lane (c,q): O[qbase+c][4q+j], +16) ----
    {
        float4 w0, w1;
        w0.x = o0[0] * rl; w0.y = o0[1] * rl; w0.z = o0[2] * rl; w0.w = o0[3] * rl;
        w1.x = o1[0] * rl; w1.y = o1[1] * rl; w1.z = o1[2] * rl; w1.w = o1[3] * rl;
        float* op = Og + bb + (size_t)(qbase + c) * 32 + quad * 4;
        *(float4*)op        = w0;   // d = quad*4..+3
        *(float4*)(op + 16) = w1;   // d = 16+quad*4..+3
    }
}

extern "C" void kernel_launch(void* const* d_in, const int* in_sizes, int n_in,
                              void* d_out, int out_size, void* d_ws, size_t ws_size,
                              hipStream_t stream) {
    (void)in_sizes; (void)n_in; (void)out_size; (void)d_ws; (void)ws_size;
    const float* Qg  = (const float*)d_in[0];
    const float* Kg  = (const float*)d_in[1];
    const float* Vg  = (const float*)d_in[2];
    const int*   VLg = (const int*)d_in[3];
    const float* Wg  = (const float*)d_in[4];
    float*       Og  = (float*)d_out;

    attn_swin_kernel<<<dim3(4096), dim3(256), 0, stream>>>(Qg, Kg, Vg, VLg, Wg, Og);
}